// Round 12
// baseline (300.168 us; speedup 1.0000x reference)
//
#include <hip/hip_runtime.h>
#include <hip/hip_bf16.h>

#define N_NODES 50000
#define N_EDGES 800000
#define IN_DIM 128
#define HIDDEN 128
#define OUT_DIM 40

#define SCAN_BS 1024
#define SCAN_BLOCKS ((N_NODES + SCAN_BS - 1) / SCAN_BS)   // 49

#define N_BUCKETS 8
#define BUCKET_NODES (N_NODES / N_BUCKETS)                // 6250
#define FIXCAP 110592                                     // records per bucket region
#define GFILL_STRIDE 16                                   // one counter per 64B line

#define BA_EDGES 1024                                     // edges per buildA block
#define BA_BLOCKS ((N_EDGES + BA_EDGES - 1) / BA_EDGES)   // 782

struct __align__(8) Edge { int s; float w; };

typedef __attribute__((ext_vector_type(8))) short bf16x8;   // MFMA A/B frag (4 VGPR)
typedef __attribute__((ext_vector_type(4))) float f32x4;    // MFMA C/D frag

// fp32 -> bf16 bits with round-to-nearest-even
__device__ __forceinline__ unsigned f32_to_bf16_bits(float f) {
    unsigned u = __float_as_uint(f);
    return (u + 0x7FFFu + ((u >> 16) & 1u)) >> 16;
}

// ---- 1) buildA: bin 1024 edges/block by dst-bucket into 8B staged records.
__global__ __launch_bounds__(256) void buildA(const int* __restrict__ src,
                                              const int* __restrict__ dst,
                                              const float* __restrict__ w,
                                              int* __restrict__ gfill,
                                              int2* __restrict__ staged)
{
    __shared__ int bin_cnt[N_BUCKETS];
    __shared__ int bin_base[N_BUCKETS];
    __shared__ int bin_fill[N_BUCKETS];
    int t = threadIdx.x;
    long long base = (long long)blockIdx.x * BA_EDGES;
    if (t < N_BUCKETS) { bin_cnt[t] = 0; bin_fill[t] = 0; }
    __syncthreads();
    int d[4], s[4]; float wv[4]; unsigned q[4]; bool ok[4];
    #pragma unroll
    for (int j = 0; j < 4; ++j) {
        long long i = base + t + j * 256;
        ok[j] = (i < N_EDGES);
        if (ok[j]) {
            d[j] = dst[i]; s[j] = src[i]; wv[j] = w[i];
            q[j] = (unsigned)d[j] / BUCKET_NODES;
            atomicAdd(&bin_cnt[q[j]], 1);
        }
    }
    __syncthreads();
    if (t < N_BUCKETS)
        bin_base[t] = atomicAdd(&gfill[t * GFILL_STRIDE], bin_cnt[t]);
    __syncthreads();
    #pragma unroll
    for (int j = 0; j < 4; ++j) {
        if (ok[j]) {
            int off = atomicAdd(&bin_fill[q[j]], 1);
            int dloc = d[j] - (int)q[j] * BUCKET_NODES;          // 13 bits
            unsigned pack = ((unsigned)dloc << 16) | f32_to_bf16_bits(wv[j]);
            staged[(long long)q[j] * FIXCAP + bin_base[q[j]] + off] =
                make_int2(s[j], (int)pack);
        }
    }
}

// ---- 2) histB: bucket-owned per-node histogram (bucket = blockIdx&7) ------
__global__ __launch_bounds__(256) void histB(const int2* __restrict__ staged,
                                             const int* __restrict__ gfill,
                                             int* __restrict__ cnt)
{
    int q   = blockIdx.x & (N_BUCKETS - 1);
    int idx = blockIdx.x >> 3;                 // 0..31 within bucket
    int n = gfill[q * GFILL_STRIDE];
    long long base = (long long)q * FIXCAP;
    int d0 = q * BUCKET_NODES;
    for (int i = idx * 256 + threadIdx.x; i < n; i += 32 * 256) {
        unsigned pack = (unsigned)staged[base + i].y;
        atomicAdd(&cnt[d0 + (int)(pack >> 16)], 1);
    }
}

// ---- 3a) per-block partial sums of cnt ------------------------------------
__global__ __launch_bounds__(SCAN_BS) void scan_partial(const int* __restrict__ cnt,
                                                        int* __restrict__ block_sums)
{
    __shared__ int red[SCAN_BS / 64];
    int i = blockIdx.x * SCAN_BS + threadIdx.x;
    int v = (i < N_NODES) ? cnt[i] : 0;
    int s = v;
    for (int off = 32; off > 0; off >>= 1) s += __shfl_down(s, off, 64);
    int wave = threadIdx.x >> 6, lane = threadIdx.x & 63;
    if (lane == 0) red[wave] = s;
    __syncthreads();
    if (threadIdx.x == 0) {
        int tt = 0;
        #pragma unroll
        for (int wv = 0; wv < SCAN_BS / 64; ++wv) tt += red[wv];
        block_sums[blockIdx.x] = tt;
    }
}

// ---- 3b) scan the 49 block sums (one wave) --------------------------------
__global__ __launch_bounds__(64) void scan_sums(int* __restrict__ block_sums,
                                                int* __restrict__ row_ptr)
{
    int t = threadIdx.x;
    int v = (t < SCAN_BLOCKS) ? block_sums[t] : 0;
    int incl = v;
    for (int off = 1; off < 64; off <<= 1) {
        int u = __shfl_up(incl, off, 64);
        if (t >= off) incl += u;
    }
    if (t < SCAN_BLOCKS) block_sums[t] = incl - v;
    if (t == 0) row_ptr[N_NODES] = N_EDGES;
}

// ---- 3c) block-local exclusive scan + offset ------------------------------
__global__ __launch_bounds__(SCAN_BS) void scan_final(const int* __restrict__ cnt,
                                                      const int* __restrict__ block_sums,
                                                      int* __restrict__ row_ptr,
                                                      int* __restrict__ cursor)
{
    __shared__ int tmp[SCAN_BS];
    int t = threadIdx.x;
    int i = blockIdx.x * SCAN_BS + t;
    int v = (i < N_NODES) ? cnt[i] : 0;
    tmp[t] = v;
    __syncthreads();
    for (int off = 1; off < SCAN_BS; off <<= 1) {
        int u = (t >= off) ? tmp[t - off] : 0;
        __syncthreads();
        tmp[t] += u;
        __syncthreads();
    }
    if (i < N_NODES) {
        int excl = tmp[t] - v + block_sums[blockIdx.x];
        row_ptr[i] = excl;
        cursor[i]  = excl;
    }
}

// ---- 4) scatterC: bucket-owned final placement ----------------------------
__global__ __launch_bounds__(256) void scatterC(const int2* __restrict__ staged,
                                                const int* __restrict__ gfill,
                                                int* __restrict__ cursor,
                                                Edge* __restrict__ edges)
{
    int q   = blockIdx.x & (N_BUCKETS - 1);
    int idx = blockIdx.x >> 3;
    int n = gfill[q * GFILL_STRIDE];
    long long base = (long long)q * FIXCAP;
    int d0 = q * BUCKET_NODES;
    for (int i = idx * 256 + threadIdx.x; i < n; i += 32 * 256) {
        int2 st = staged[base + i];
        unsigned pack = (unsigned)st.y;
        int d = d0 + (int)(pack >> 16);
        int pos = atomicAdd(&cursor[d], 1);
        Edge ed; ed.s = st.x; ed.w = __uint_as_float((pack & 0xFFFFu) << 16);
        edges[pos] = ed;
    }
}

// ---- w1_swizzle: W1 (fp32 [K=128][N=128]) -> bf16 B-fragment order --------
__global__ __launch_bounds__(256) void w1_swizzle(const float* __restrict__ W1,
                                                  bf16x8* __restrict__ W1s)
{
    int tid = blockIdx.x * 256 + threadIdx.x;     // 0..2047
    int lane = tid & 63;
    int nt = (tid >> 6) & 7;
    int ks = tid >> 9;
    int m = lane & 15, quad = lane >> 4;
    bf16x8 frag;
    #pragma unroll
    for (int j = 0; j < 8; ++j) {
        int k = ks * 32 + quad * 8 + j;
        frag[j] = (short)f32_to_bf16_bits(W1[k * HIDDEN + nt * 16 + m]);
    }
    W1s[tid] = frag;
}

// ---- gemm1_mfma: y = x @ W1 via v_mfma_f32_16x16x32_bf16 ------------------
__global__ __launch_bounds__(256) void gemm1_mfma(const float* __restrict__ x,
                                                  const bf16x8* __restrict__ W1s,
                                                  __hip_bfloat16* __restrict__ y)
{
    int wv = threadIdx.x >> 6;
    int lane = threadIdx.x & 63;
    int m = lane & 15, quad = lane >> 4;
    int row0 = blockIdx.x * 64 + wv * 16;
    int arow = row0 + m;
    if (arow >= N_NODES) arow = N_NODES - 1;      // clamp loads; stores guarded

    bf16x8 afrag[4];
    #pragma unroll
    for (int ks = 0; ks < 4; ++ks) {
        const float4* xp = (const float4*)(x + (long long)arow * IN_DIM + ks * 32 + quad * 8);
        float4 a0 = xp[0], a1 = xp[1];
        afrag[ks][0] = (short)f32_to_bf16_bits(a0.x);
        afrag[ks][1] = (short)f32_to_bf16_bits(a0.y);
        afrag[ks][2] = (short)f32_to_bf16_bits(a0.z);
        afrag[ks][3] = (short)f32_to_bf16_bits(a0.w);
        afrag[ks][4] = (short)f32_to_bf16_bits(a1.x);
        afrag[ks][5] = (short)f32_to_bf16_bits(a1.y);
        afrag[ks][6] = (short)f32_to_bf16_bits(a1.z);
        afrag[ks][7] = (short)f32_to_bf16_bits(a1.w);
    }

    f32x4 acc[8];
    #pragma unroll
    for (int nt = 0; nt < 8; ++nt) acc[nt] = (f32x4){0.f, 0.f, 0.f, 0.f};

    #pragma unroll
    for (int ks = 0; ks < 4; ++ks) {
        #pragma unroll
        for (int nt = 0; nt < 8; ++nt) {
            bf16x8 bfrag = W1s[(ks * 8 + nt) * 64 + lane];
            acc[nt] = __builtin_amdgcn_mfma_f32_16x16x32_bf16(afrag[ks], bfrag, acc[nt], 0, 0, 0);
        }
    }

    #pragma unroll
    for (int nt = 0; nt < 8; ++nt) {
        #pragma unroll
        for (int r = 0; r < 4; ++r) {
            int rrow = row0 + quad * 4 + r;
            if (rrow < N_NODES)
                y[(long long)rrow * HIDDEN + nt * 16 + m] = __float2bfloat16(acc[nt][r]);
        }
    }
}

// ---- spmm1 (feature-chunked): h1 = relu(A @ y + b1) -----------------------
// chunk = (blockIdx>>1)&3 -> each 32-col chunk (one 64B line per y-row,
// 3.2 MB working set) gathered by one XCD pair -> L2-resident.
// 16 lanes/node (bf16x2 x16 = 32 cols), 16 nodes per 256-thread block.
__global__ __launch_bounds__(256) void spmm1_kernel(const int* __restrict__ row_ptr,
                                                    const Edge* __restrict__ edges,
                                                    const __hip_bfloat16* __restrict__ y,
                                                    const float* __restrict__ b1,
                                                    __hip_bfloat16* __restrict__ h1)
{
    int b = blockIdx.x;
    int chunk = (b >> 1) & 3;
    int node_group = (b >> 3) * 2 + (b & 1);       // 0..3125
    int t = threadIdx.x;
    int wv = t >> 6, lane = t & 63;
    int node = node_group * 16 + wv * 4 + (lane >> 4);
    if (node >= N_NODES) return;
    int sub = lane & 15;                            // col-pair within chunk
    int col2 = chunk * 16 + sub;                    // bf16x2 index, 0..63
    int beg = row_ptr[node];
    int end = row_ptr[node + 1];
    const __hip_bfloat162* yv = (const __hip_bfloat162*)y;
    float ax = 0.f, ay = 0.f;
    int j = beg;
    for (; j + 3 < end; j += 4) {
        Edge e0 = edges[j];
        Edge e1 = edges[j + 1];
        Edge e2 = edges[j + 2];
        Edge e3 = edges[j + 3];
        __hip_bfloat162 v0 = yv[(long long)e0.s * 64 + col2];
        __hip_bfloat162 v1 = yv[(long long)e1.s * 64 + col2];
        __hip_bfloat162 v2 = yv[(long long)e2.s * 64 + col2];
        __hip_bfloat162 v3 = yv[(long long)e3.s * 64 + col2];
        ax = fmaf(e0.w, __low2float(v0), ax);  ay = fmaf(e0.w, __high2float(v0), ay);
        ax = fmaf(e1.w, __low2float(v1), ax);  ay = fmaf(e1.w, __high2float(v1), ay);
        ax = fmaf(e2.w, __low2float(v2), ax);  ay = fmaf(e2.w, __high2float(v2), ay);
        ax = fmaf(e3.w, __low2float(v3), ax);  ay = fmaf(e3.w, __high2float(v3), ay);
    }
    for (; j < end; ++j) {
        Edge e0 = edges[j];
        __hip_bfloat162 v0 = yv[(long long)e0.s * 64 + col2];
        ax = fmaf(e0.w, __low2float(v0), ax);
        ay = fmaf(e0.w, __high2float(v0), ay);
    }
    float2 bv = ((const float2*)b1)[col2];
    __hip_bfloat162 hv;
    hv.x = __float2bfloat16(fmaxf(ax + bv.x, 0.f));
    hv.y = __float2bfloat16(fmaxf(ay + bv.y, 0.f));
    ((__hip_bfloat162*)h1)[(long long)node * 64 + col2] = hv;
}

// ---- gemm2: g = h1 @ W2 (bf16 in, bf16 out), 8 rows/block -----------------
#define G2_ROWS 8
__global__ __launch_bounds__(64) void gemm2_kernel(const __hip_bfloat16* __restrict__ h1,
                                                   const float* __restrict__ W2,
                                                   __hip_bfloat16* __restrict__ g)
{
    __shared__ float xs[G2_ROWS][HIDDEN];
    int row0 = blockIdx.x * G2_ROWS;
    int t = threadIdx.x;
    #pragma unroll
    for (int r = 0; r < G2_ROWS; ++r) {
        xs[r][t]      = __bfloat162float(h1[(long long)(row0 + r) * HIDDEN + t]);
        xs[r][t + 64] = __bfloat162float(h1[(long long)(row0 + r) * HIDDEN + t + 64]);
    }
    __syncthreads();
    if (t >= OUT_DIM) return;
    float acc[G2_ROWS];
    #pragma unroll
    for (int r = 0; r < G2_ROWS; ++r) acc[r] = 0.f;
    #pragma unroll 4
    for (int k = 0; k < HIDDEN; ++k) {
        float wv = W2[k * OUT_DIM + t];
        #pragma unroll
        for (int r = 0; r < G2_ROWS; ++r)
            acc[r] = fmaf(xs[r][k], wv, acc[r]);
    }
    #pragma unroll
    for (int r = 0; r < G2_ROWS; ++r)
        g[(long long)(row0 + r) * OUT_DIM + t] = __float2bfloat16(acc[r]);
}

// ---- spmm2: out = A @ g + b2; wave/node, 40 active lanes ------------------
__global__ __launch_bounds__(256) void spmm2_kernel(const int* __restrict__ row_ptr,
                                                    const Edge* __restrict__ edges,
                                                    const __hip_bfloat16* __restrict__ g,
                                                    const float* __restrict__ b2,
                                                    float* __restrict__ out)
{
    int node = blockIdx.x * 4 + (threadIdx.x >> 6);
    int lane = threadIdx.x & 63;
    if (node >= N_NODES) return;
    if (lane >= OUT_DIM) return;
    int beg = row_ptr[node];
    int end = row_ptr[node + 1];
    float acc = 0.f;
    int j = beg;
    for (; j + 3 < end; j += 4) {
        Edge e0 = edges[j];
        Edge e1 = edges[j + 1];
        Edge e2 = edges[j + 2];
        Edge e3 = edges[j + 3];
        float v0 = __bfloat162float(g[(long long)e0.s * OUT_DIM + lane]);
        float v1 = __bfloat162float(g[(long long)e1.s * OUT_DIM + lane]);
        float v2 = __bfloat162float(g[(long long)e2.s * OUT_DIM + lane]);
        float v3 = __bfloat162float(g[(long long)e3.s * OUT_DIM + lane]);
        acc = fmaf(e0.w, v0, acc);
        acc = fmaf(e1.w, v1, acc);
        acc = fmaf(e2.w, v2, acc);
        acc = fmaf(e3.w, v3, acc);
    }
    for (; j < end; ++j) {
        Edge e0 = edges[j];
        acc = fmaf(e0.w, __bfloat162float(g[(long long)e0.s * OUT_DIM + lane]), acc);
    }
    out[(long long)node * OUT_DIM + lane] = acc + b2[lane];
}

extern "C" void kernel_launch(void* const* d_in, const int* in_sizes, int n_in,
                              void* d_out, int out_size, void* d_ws, size_t ws_size,
                              hipStream_t stream)
{
    const float* x    = (const float*)d_in[0];
    const int*   esrc = (const int*)  d_in[1];
    const int*   edst = (const int*)  d_in[2];
    const float* ew   = (const float*)d_in[3];
    const float* W1   = (const float*)d_in[4];
    const float* b1   = (const float*)d_in[5];
    const float* W2   = (const float*)d_in[6];
    const float* b2   = (const float*)d_in[7];
    float* out = (float*)d_out;

    // workspace layout (~44 MB)
    __hip_bfloat16* y  = (__hip_bfloat16*)d_ws;                  // 12.8 MB
    __hip_bfloat16* h1 = y  + (size_t)N_NODES * HIDDEN;          // 12.8 MB
    __hip_bfloat16* g  = h1 + (size_t)N_NODES * HIDDEN;          // 4.0 MB
    int2* staged    = (int2*)(g + (size_t)N_NODES * OUT_DIM);    // 7.1 MB
    Edge* edges     = (Edge*)(staged + (size_t)N_BUCKETS * FIXCAP); // 6.4 MB
    int* gfill      = (int*)(edges + N_EDGES);                   // 128 ints (line-padded)
    int* cnt        = gfill + N_BUCKETS * GFILL_STRIDE;          // 200 KB
    int* row_ptr    = cnt + 50176;                               // 50001 (pad 50176)
    int* cursor     = row_ptr + 50176;
    int* block_sums = cursor + 50176;                            // 64 ints
    bf16x8* W1s     = (bf16x8*)(block_sums + 64);                // 32 KB swizzled W1

    // CSR build: bin -> bucket-local hist -> scan -> bucket-local placement
    hipMemsetAsync(gfill, 0, (N_BUCKETS * GFILL_STRIDE + 50176) * sizeof(int), stream);
    buildA<<<BA_BLOCKS, 256, 0, stream>>>(esrc, edst, ew, gfill, staged);
    histB<<<32 * N_BUCKETS, 256, 0, stream>>>(staged, gfill, cnt);
    scan_partial<<<SCAN_BLOCKS, SCAN_BS, 0, stream>>>(cnt, block_sums);
    scan_sums<<<1, 64, 0, stream>>>(block_sums, row_ptr);
    scan_final<<<SCAN_BLOCKS, SCAN_BS, 0, stream>>>(cnt, block_sums, row_ptr, cursor);
    scatterC<<<32 * N_BUCKETS, 256, 0, stream>>>(staged, gfill, cursor, edges);

    // y = x @ W1 (MFMA)
    w1_swizzle<<<8, 256, 0, stream>>>(W1, W1s);
    gemm1_mfma<<<(N_NODES + 63) / 64, 256, 0, stream>>>(x, W1s, y);
    // h1 = relu(A @ y + b1), feature-chunked for per-XCD L2 residency
    spmm1_kernel<<<3126 * 4, 256, 0, stream>>>(row_ptr, edges, y, b1, h1);
    // g = h1 @ W2
    gemm2_kernel<<<N_NODES / G2_ROWS, 64, 0, stream>>>(h1, W2, g);
    // out = A @ g + b2
    spmm2_kernel<<<(N_NODES + 3) / 4, 256, 0, stream>>>(row_ptr, edges, g, b2, out);
}

// Round 13
// 277.607 us; speedup vs baseline: 1.0813x; 1.0813x over previous
//
#include <hip/hip_runtime.h>
#include <hip/hip_bf16.h>

#define N_NODES 50000
#define N_EDGES 800000
#define IN_DIM 128
#define HIDDEN 128
#define OUT_DIM 40

#define SCAN_BS 1024
#define SCAN_BLOCKS ((N_NODES + SCAN_BS - 1) / SCAN_BS)   // 49

#define N_BUCKETS 8
#define BUCKET_NODES (N_NODES / N_BUCKETS)                // 6250
#define HIST_STRIDE 50176                                 // line-aligned copy stride
#define FIXCAP 110592                                     // records per bucket region
#define GFILL_STRIDE 16                                   // one counter per 64B line

#define BA_EDGES 1024                                     // edges per buildA block
#define BA_BLOCKS ((N_EDGES + BA_EDGES - 1) / BA_EDGES)   // 782

struct __align__(8) Edge { int s; float w; };

typedef __attribute__((ext_vector_type(8))) short bf16x8;   // MFMA A/B frag (4 VGPR)
typedef __attribute__((ext_vector_type(4))) float f32x4;    // MFMA C/D frag

// fp32 -> bf16 bits with round-to-nearest-even
__device__ __forceinline__ unsigned f32_to_bf16_bits(float f) {
    unsigned u = __float_as_uint(f);
    return (u + 0x7FFFu + ((u >> 16) & 1u)) >> 16;
}

// ---- 1) buildA: ONE pass over edges.
// (a) per-node histogram into XCD-private copy blockIdx&7 (non-returning
//     own-L2 atomics); (b) bin by dst-bucket into 8B staged records with
//     line-padded global reservations (782 per counter).
__global__ __launch_bounds__(256) void buildA(const int* __restrict__ src,
                                              const int* __restrict__ dst,
                                              const float* __restrict__ w,
                                              int* __restrict__ hist8,
                                              int* __restrict__ gfill,
                                              int2* __restrict__ staged)
{
    __shared__ int bin_cnt[N_BUCKETS];
    __shared__ int bin_base[N_BUCKETS];
    __shared__ int bin_fill[N_BUCKETS];
    int t = threadIdx.x;
    long long base = (long long)blockIdx.x * BA_EDGES;
    if (t < N_BUCKETS) { bin_cnt[t] = 0; bin_fill[t] = 0; }
    __syncthreads();
    int copy = blockIdx.x & (N_BUCKETS - 1);
    int d[4], s[4]; float wv[4]; unsigned q[4]; bool ok[4];
    #pragma unroll
    for (int j = 0; j < 4; ++j) {
        long long i = base + t + j * 256;
        ok[j] = (i < N_EDGES);
        if (ok[j]) {
            d[j] = dst[i]; s[j] = src[i]; wv[j] = w[i];
            q[j] = (unsigned)d[j] / BUCKET_NODES;
            atomicAdd(&hist8[copy * HIST_STRIDE + d[j]], 1);
            atomicAdd(&bin_cnt[q[j]], 1);
        }
    }
    __syncthreads();
    if (t < N_BUCKETS)
        bin_base[t] = atomicAdd(&gfill[t * GFILL_STRIDE], bin_cnt[t]);
    __syncthreads();
    #pragma unroll
    for (int j = 0; j < 4; ++j) {
        if (ok[j]) {
            int off = atomicAdd(&bin_fill[q[j]], 1);
            int dloc = d[j] - (int)q[j] * BUCKET_NODES;          // 13 bits
            unsigned pack = ((unsigned)dloc << 16) | f32_to_bf16_bits(wv[j]);
            staged[(long long)q[j] * FIXCAP + bin_base[q[j]] + off] =
                make_int2(s[j], (int)pack);
        }
    }
}

// ---- 2a) reduce 8 histogram copies -> cnt, plus per-block partial sums ----
__global__ __launch_bounds__(SCAN_BS) void scan_partial(const int* __restrict__ hist8,
                                                        int* __restrict__ cnt,
                                                        int* __restrict__ block_sums)
{
    __shared__ int red[SCAN_BS / 64];
    int i = blockIdx.x * SCAN_BS + threadIdx.x;
    int v = 0;
    if (i < N_NODES) {
        #pragma unroll
        for (int c = 0; c < N_BUCKETS; ++c) v += hist8[c * HIST_STRIDE + i];
        cnt[i] = v;
    }
    int s = v;
    for (int off = 32; off > 0; off >>= 1) s += __shfl_down(s, off, 64);
    int wave = threadIdx.x >> 6, lane = threadIdx.x & 63;
    if (lane == 0) red[wave] = s;
    __syncthreads();
    if (threadIdx.x == 0) {
        int tt = 0;
        #pragma unroll
        for (int wv = 0; wv < SCAN_BS / 64; ++wv) tt += red[wv];
        block_sums[blockIdx.x] = tt;
    }
}

// ---- 2b) block-local exclusive scan; inline prefix over raw block_sums ----
__global__ __launch_bounds__(SCAN_BS) void scan_final(const int* __restrict__ cnt,
                                                      const int* __restrict__ block_sums,
                                                      int* __restrict__ row_ptr,
                                                      int* __restrict__ cursor)
{
    __shared__ int tmp[SCAN_BS];
    __shared__ int blk_off;
    int t = threadIdx.x;
    int i = blockIdx.x * SCAN_BS + t;
    if (t == 0) {
        int s = 0;
        for (int j = 0; j < (int)blockIdx.x; ++j) s += block_sums[j];
        blk_off = s;
        if (blockIdx.x == 0) row_ptr[N_NODES] = N_EDGES;
    }
    int v = (i < N_NODES) ? cnt[i] : 0;
    tmp[t] = v;
    __syncthreads();
    for (int off = 1; off < SCAN_BS; off <<= 1) {
        int u = (t >= off) ? tmp[t - off] : 0;
        __syncthreads();
        tmp[t] += u;
        __syncthreads();
    }
    if (i < N_NODES) {
        int excl = tmp[t] - v + blk_off;
        row_ptr[i] = excl;
        cursor[i]  = excl;
    }
}

// ---- 3) scatterC: bucket-owned final placement ----------------------------
__global__ __launch_bounds__(256) void scatterC(const int2* __restrict__ staged,
                                                const int* __restrict__ gfill,
                                                int* __restrict__ cursor,
                                                Edge* __restrict__ edges)
{
    int q   = blockIdx.x & (N_BUCKETS - 1);
    int idx = blockIdx.x >> 3;
    int n = gfill[q * GFILL_STRIDE];
    long long base = (long long)q * FIXCAP;
    int d0 = q * BUCKET_NODES;
    for (int i = idx * 256 + threadIdx.x; i < n; i += 32 * 256) {
        int2 st = staged[base + i];
        unsigned pack = (unsigned)st.y;
        int d = d0 + (int)(pack >> 16);
        int pos = atomicAdd(&cursor[d], 1);
        Edge ed; ed.s = st.x; ed.w = __uint_as_float((pack & 0xFFFFu) << 16);
        edges[pos] = ed;
    }
}

// ---- gemm1_mfma: y = x @ W1 via v_mfma_f32_16x16x32_bf16 ------------------
// W1 swizzled into LDS by each block (32 KB); 4 waves/block, wave = 16 rows.
// A: m=lane&15, k=quad*8+j ; B: n=lane&15, k=quad*8+j ; D: col=lane&15,
// row=quad*4+reg (verified round 11: absmax unchanged).
__global__ __launch_bounds__(256) void gemm1_mfma(const float* __restrict__ x,
                                                  const float* __restrict__ W1,
                                                  __hip_bfloat16* __restrict__ y)
{
    __shared__ bf16x8 w1s[2048];                  // 32 KB
    int t = threadIdx.x;
    for (int f = t; f < 2048; f += 256) {         // 8 frags per thread
        int lane = f & 63;
        int nt = (f >> 6) & 7;
        int ks = f >> 9;
        int m = lane & 15, quad = lane >> 4;
        bf16x8 frag;
        #pragma unroll
        for (int j = 0; j < 8; ++j) {
            int k = ks * 32 + quad * 8 + j;
            frag[j] = (short)f32_to_bf16_bits(W1[k * HIDDEN + nt * 16 + m]);
        }
        w1s[f] = frag;
    }
    __syncthreads();

    int wv = t >> 6;
    int lane = t & 63;
    int m = lane & 15, quad = lane >> 4;
    int row0 = blockIdx.x * 64 + wv * 16;
    int arow = row0 + m;
    if (arow >= N_NODES) arow = N_NODES - 1;      // clamp loads; stores guarded

    bf16x8 afrag[4];
    #pragma unroll
    for (int ks = 0; ks < 4; ++ks) {
        const float4* xp = (const float4*)(x + (long long)arow * IN_DIM + ks * 32 + quad * 8);
        float4 a0 = xp[0], a1 = xp[1];
        afrag[ks][0] = (short)f32_to_bf16_bits(a0.x);
        afrag[ks][1] = (short)f32_to_bf16_bits(a0.y);
        afrag[ks][2] = (short)f32_to_bf16_bits(a0.z);
        afrag[ks][3] = (short)f32_to_bf16_bits(a0.w);
        afrag[ks][4] = (short)f32_to_bf16_bits(a1.x);
        afrag[ks][5] = (short)f32_to_bf16_bits(a1.y);
        afrag[ks][6] = (short)f32_to_bf16_bits(a1.z);
        afrag[ks][7] = (short)f32_to_bf16_bits(a1.w);
    }

    f32x4 acc[8];
    #pragma unroll
    for (int nt = 0; nt < 8; ++nt) acc[nt] = (f32x4){0.f, 0.f, 0.f, 0.f};

    #pragma unroll
    for (int ks = 0; ks < 4; ++ks) {
        #pragma unroll
        for (int nt = 0; nt < 8; ++nt) {
            bf16x8 bfrag = w1s[(ks * 8 + nt) * 64 + lane];
            acc[nt] = __builtin_amdgcn_mfma_f32_16x16x32_bf16(afrag[ks], bfrag, acc[nt], 0, 0, 0);
        }
    }

    #pragma unroll
    for (int nt = 0; nt < 8; ++nt) {
        #pragma unroll
        for (int r = 0; r < 4; ++r) {
            int rrow = row0 + quad * 4 + r;
            if (rrow < N_NODES)
                y[(long long)rrow * HIDDEN + nt * 16 + m] = __float2bfloat16(acc[nt][r]);
        }
    }
}

// ---- spmm1: h1 = relu(A @ y + b1); wave/node, bf16x2 per lane (monolithic)-
__global__ __launch_bounds__(256) void spmm1_kernel(const int* __restrict__ row_ptr,
                                                    const Edge* __restrict__ edges,
                                                    const __hip_bfloat16* __restrict__ y,
                                                    const float* __restrict__ b1,
                                                    __hip_bfloat16* __restrict__ h1)
{
    int node = blockIdx.x * 4 + (threadIdx.x >> 6);
    int lane = threadIdx.x & 63;
    if (node >= N_NODES) return;
    int beg = row_ptr[node];
    int end = row_ptr[node + 1];
    const __hip_bfloat162* yv = (const __hip_bfloat162*)y;
    float ax = 0.f, ay = 0.f;
    int j = beg;
    for (; j + 3 < end; j += 4) {
        Edge e0 = edges[j];
        Edge e1 = edges[j + 1];
        Edge e2 = edges[j + 2];
        Edge e3 = edges[j + 3];
        __hip_bfloat162 v0 = yv[(long long)e0.s * 64 + lane];
        __hip_bfloat162 v1 = yv[(long long)e1.s * 64 + lane];
        __hip_bfloat162 v2 = yv[(long long)e2.s * 64 + lane];
        __hip_bfloat162 v3 = yv[(long long)e3.s * 64 + lane];
        ax = fmaf(e0.w, __low2float(v0), ax);  ay = fmaf(e0.w, __high2float(v0), ay);
        ax = fmaf(e1.w, __low2float(v1), ax);  ay = fmaf(e1.w, __high2float(v1), ay);
        ax = fmaf(e2.w, __low2float(v2), ax);  ay = fmaf(e2.w, __high2float(v2), ay);
        ax = fmaf(e3.w, __low2float(v3), ax);  ay = fmaf(e3.w, __high2float(v3), ay);
    }
    for (; j < end; ++j) {
        Edge e0 = edges[j];
        __hip_bfloat162 v0 = yv[(long long)e0.s * 64 + lane];
        ax = fmaf(e0.w, __low2float(v0), ax);
        ay = fmaf(e0.w, __high2float(v0), ay);
    }
    float2 bv = ((const float2*)b1)[lane];
    __hip_bfloat162 hv;
    hv.x = __float2bfloat16(fmaxf(ax + bv.x, 0.f));
    hv.y = __float2bfloat16(fmaxf(ay + bv.y, 0.f));
    ((__hip_bfloat162*)h1)[(long long)node * 64 + lane] = hv;
}

// ---- gemm2: g = h1 @ W2 (bf16 in, bf16 out), 8 rows/block -----------------
#define G2_ROWS 8
__global__ __launch_bounds__(64) void gemm2_kernel(const __hip_bfloat16* __restrict__ h1,
                                                   const float* __restrict__ W2,
                                                   __hip_bfloat16* __restrict__ g)
{
    __shared__ float xs[G2_ROWS][HIDDEN];
    int row0 = blockIdx.x * G2_ROWS;
    int t = threadIdx.x;
    #pragma unroll
    for (int r = 0; r < G2_ROWS; ++r) {
        xs[r][t]      = __bfloat162float(h1[(long long)(row0 + r) * HIDDEN + t]);
        xs[r][t + 64] = __bfloat162float(h1[(long long)(row0 + r) * HIDDEN + t + 64]);
    }
    __syncthreads();
    if (t >= OUT_DIM) return;
    float acc[G2_ROWS];
    #pragma unroll
    for (int r = 0; r < G2_ROWS; ++r) acc[r] = 0.f;
    #pragma unroll 4
    for (int k = 0; k < HIDDEN; ++k) {
        float wv = W2[k * OUT_DIM + t];
        #pragma unroll
        for (int r = 0; r < G2_ROWS; ++r)
            acc[r] = fmaf(xs[r][k], wv, acc[r]);
    }
    #pragma unroll
    for (int r = 0; r < G2_ROWS; ++r)
        g[(long long)(row0 + r) * OUT_DIM + t] = __float2bfloat16(acc[r]);
}

// ---- spmm2: out = A @ g + b2; wave/node, 40 active lanes ------------------
__global__ __launch_bounds__(256) void spmm2_kernel(const int* __restrict__ row_ptr,
                                                    const Edge* __restrict__ edges,
                                                    const __hip_bfloat16* __restrict__ g,
                                                    const float* __restrict__ b2,
                                                    float* __restrict__ out)
{
    int node = blockIdx.x * 4 + (threadIdx.x >> 6);
    int lane = threadIdx.x & 63;
    if (node >= N_NODES) return;
    if (lane >= OUT_DIM) return;
    int beg = row_ptr[node];
    int end = row_ptr[node + 1];
    float acc = 0.f;
    int j = beg;
    for (; j + 3 < end; j += 4) {
        Edge e0 = edges[j];
        Edge e1 = edges[j + 1];
        Edge e2 = edges[j + 2];
        Edge e3 = edges[j + 3];
        float v0 = __bfloat162float(g[(long long)e0.s * OUT_DIM + lane]);
        float v1 = __bfloat162float(g[(long long)e1.s * OUT_DIM + lane]);
        float v2 = __bfloat162float(g[(long long)e2.s * OUT_DIM + lane]);
        float v3 = __bfloat162float(g[(long long)e3.s * OUT_DIM + lane]);
        acc = fmaf(e0.w, v0, acc);
        acc = fmaf(e1.w, v1, acc);
        acc = fmaf(e2.w, v2, acc);
        acc = fmaf(e3.w, v3, acc);
    }
    for (; j < end; ++j) {
        Edge e0 = edges[j];
        acc = fmaf(e0.w, __bfloat162float(g[(long long)e0.s * OUT_DIM + lane]), acc);
    }
    out[(long long)node * OUT_DIM + lane] = acc + b2[lane];
}

extern "C" void kernel_launch(void* const* d_in, const int* in_sizes, int n_in,
                              void* d_out, int out_size, void* d_ws, size_t ws_size,
                              hipStream_t stream)
{
    const float* x    = (const float*)d_in[0];
    const int*   esrc = (const int*)  d_in[1];
    const int*   edst = (const int*)  d_in[2];
    const float* ew   = (const float*)d_in[3];
    const float* W1   = (const float*)d_in[4];
    const float* b1   = (const float*)d_in[5];
    const float* W2   = (const float*)d_in[6];
    const float* b2   = (const float*)d_in[7];
    float* out = (float*)d_out;

    // workspace layout (~44 MB)
    __hip_bfloat16* y  = (__hip_bfloat16*)d_ws;                  // 12.8 MB
    __hip_bfloat16* h1 = y  + (size_t)N_NODES * HIDDEN;          // 12.8 MB
    __hip_bfloat16* g  = h1 + (size_t)N_NODES * HIDDEN;          // 4.0 MB
    int2* staged    = (int2*)(g + (size_t)N_NODES * OUT_DIM);    // 7.1 MB
    Edge* edges     = (Edge*)(staged + (size_t)N_BUCKETS * FIXCAP); // 6.4 MB
    int* hist8      = (int*)(edges + N_EDGES);                   // 1.6 MB
    int* gfill      = hist8 + N_BUCKETS * HIST_STRIDE;           // 128 ints (line-padded)
    int* cnt        = gfill + N_BUCKETS * GFILL_STRIDE;          // 200 KB
    int* row_ptr    = cnt + 50176;                               // 50001 (pad 50176)
    int* cursor     = row_ptr + 50176;
    int* block_sums = cursor + 50176;                            // 64 ints

    // CSR build: single-pass hist+bin -> scan -> bucket-owned placement
    hipMemsetAsync(hist8, 0,
                   (N_BUCKETS * HIST_STRIDE + N_BUCKETS * GFILL_STRIDE) * sizeof(int),
                   stream);
    buildA<<<BA_BLOCKS, 256, 0, stream>>>(esrc, edst, ew, hist8, gfill, staged);
    scan_partial<<<SCAN_BLOCKS, SCAN_BS, 0, stream>>>(hist8, cnt, block_sums);
    scan_final<<<SCAN_BLOCKS, SCAN_BS, 0, stream>>>(cnt, block_sums, row_ptr, cursor);
    scatterC<<<32 * N_BUCKETS, 256, 0, stream>>>(staged, gfill, cursor, edges);

    // y = x @ W1 (MFMA, W1 swizzled in-kernel via LDS)
    gemm1_mfma<<<(N_NODES + 63) / 64, 256, 0, stream>>>(x, W1, y);
    // h1 = relu(A @ y + b1)
    spmm1_kernel<<<(N_NODES + 3) / 4, 256, 0, stream>>>(row_ptr, edges, y, b1, h1);
    // g = h1 @ W2
    gemm2_kernel<<<N_NODES / G2_ROWS, 64, 0, stream>>>(h1, W2, g);
    // out = A @ g + b2
    spmm2_kernel<<<(N_NODES + 3) / 4, 256, 0, stream>>>(row_ptr, edges, g, b2, out);
}

// Round 14
// 268.911 us; speedup vs baseline: 1.1162x; 1.0323x over previous
//
#include <hip/hip_runtime.h>
#include <hip/hip_bf16.h>

#define N_NODES 50000
#define N_EDGES 800000
#define IN_DIM 128
#define HIDDEN 128
#define OUT_DIM 40

#define SCAN_BS 1024
#define SCAN_BLOCKS ((N_NODES + SCAN_BS - 1) / SCAN_BS)   // 49

#define N_BUCKETS 8
#define N_GROUPS 8
#define BUCKET_NODES (N_NODES / N_BUCKETS)                // 6250
#define HIST_STRIDE 50176                                 // line-aligned copy stride
#define SUBCAP 16384                                      // records per (bucket,group): +37 sigma
#define GFILL_STRIDE 16                                   // one counter per 64B line

#define BA_EDGES 1024                                     // edges per buildA block
#define BA_BLOCKS ((N_EDGES + BA_EDGES - 1) / BA_EDGES)   // 782

struct __align__(8) Edge { int s; float w; };

typedef __attribute__((ext_vector_type(8))) short bf16x8;   // MFMA A/B frag (4 VGPR)
typedef __attribute__((ext_vector_type(4))) float f32x4;    // MFMA C/D frag

// fp32 -> bf16 bits with round-to-nearest-even
__device__ __forceinline__ unsigned f32_to_bf16_bits(float f) {
    unsigned u = __float_as_uint(f);
    return (u + 0x7FFFu + ((u >> 16) & 1u)) >> 16;
}

// ---- 1) buildA: ONE pass over edges.
// (a) per-node histogram into XCD-private copy blockIdx&7;
// (b) bin by dst-bucket; rank via a SINGLE LDS atomic; reservation goes to
//     gfill[bucket][group] (group = blockIdx&7) so each counter line is
//     RMW'd by one XCD only -> short, L2-local serial chains.
__global__ __launch_bounds__(256) void buildA(const int* __restrict__ src,
                                              const int* __restrict__ dst,
                                              const float* __restrict__ w,
                                              int* __restrict__ hist8,
                                              int* __restrict__ gfill,
                                              int2* __restrict__ staged)
{
    __shared__ int bin_cnt[N_BUCKETS];
    __shared__ int bin_base[N_BUCKETS];
    int t = threadIdx.x;
    long long base = (long long)blockIdx.x * BA_EDGES;
    if (t < N_BUCKETS) bin_cnt[t] = 0;
    __syncthreads();
    int grp = blockIdx.x & (N_GROUPS - 1);
    int d[4], s[4]; float wv[4]; unsigned q[4]; int rank[4]; bool ok[4];
    #pragma unroll
    for (int j = 0; j < 4; ++j) {
        long long i = base + t + j * 256;
        ok[j] = (i < N_EDGES);
        if (ok[j]) {
            d[j] = dst[i]; s[j] = src[i]; wv[j] = w[i];
            q[j] = (unsigned)d[j] / BUCKET_NODES;
            atomicAdd(&hist8[grp * HIST_STRIDE + d[j]], 1);
            rank[j] = atomicAdd(&bin_cnt[q[j]], 1);      // single LDS atomic
        }
    }
    __syncthreads();
    if (t < N_BUCKETS)
        bin_base[t] = atomicAdd(&gfill[(t * N_GROUPS + grp) * GFILL_STRIDE],
                                bin_cnt[t]);
    __syncthreads();
    #pragma unroll
    for (int j = 0; j < 4; ++j) {
        if (ok[j]) {
            int dloc = d[j] - (int)q[j] * BUCKET_NODES;          // 13 bits
            unsigned pack = ((unsigned)dloc << 16) | f32_to_bf16_bits(wv[j]);
            long long pos = (long long)(q[j] * N_GROUPS + grp) * SUBCAP
                          + bin_base[q[j]] + rank[j];
            staged[pos] = make_int2(s[j], (int)pack);
        }
    }
}

// ---- 2a) reduce 8 histogram copies -> cnt, plus per-block partial sums ----
__global__ __launch_bounds__(SCAN_BS) void scan_partial(const int* __restrict__ hist8,
                                                        int* __restrict__ cnt,
                                                        int* __restrict__ block_sums)
{
    __shared__ int red[SCAN_BS / 64];
    int i = blockIdx.x * SCAN_BS + threadIdx.x;
    int v = 0;
    if (i < N_NODES) {
        #pragma unroll
        for (int c = 0; c < N_GROUPS; ++c) v += hist8[c * HIST_STRIDE + i];
        cnt[i] = v;
    }
    int s = v;
    for (int off = 32; off > 0; off >>= 1) s += __shfl_down(s, off, 64);
    int wave = threadIdx.x >> 6, lane = threadIdx.x & 63;
    if (lane == 0) red[wave] = s;
    __syncthreads();
    if (threadIdx.x == 0) {
        int tt = 0;
        #pragma unroll
        for (int wv = 0; wv < SCAN_BS / 64; ++wv) tt += red[wv];
        block_sums[blockIdx.x] = tt;
    }
}

// ---- 2b) block-local exclusive scan; inline prefix over raw block_sums ----
__global__ __launch_bounds__(SCAN_BS) void scan_final(const int* __restrict__ cnt,
                                                      const int* __restrict__ block_sums,
                                                      int* __restrict__ row_ptr,
                                                      int* __restrict__ cursor)
{
    __shared__ int tmp[SCAN_BS];
    __shared__ int blk_off;
    int t = threadIdx.x;
    int i = blockIdx.x * SCAN_BS + t;
    if (t == 0) {
        int s = 0;
        for (int j = 0; j < (int)blockIdx.x; ++j) s += block_sums[j];
        blk_off = s;
        if (blockIdx.x == 0) row_ptr[N_NODES] = N_EDGES;
    }
    int v = (i < N_NODES) ? cnt[i] : 0;
    tmp[t] = v;
    __syncthreads();
    for (int off = 1; off < SCAN_BS; off <<= 1) {
        int u = (t >= off) ? tmp[t - off] : 0;
        __syncthreads();
        tmp[t] += u;
        __syncthreads();
    }
    if (i < N_NODES) {
        int excl = tmp[t] - v + blk_off;
        row_ptr[i] = excl;
        cursor[i]  = excl;
    }
}

// ---- 3) scatterC: bucket-owned final placement over 8 sub-segments --------
__global__ __launch_bounds__(256) void scatterC(const int2* __restrict__ staged,
                                                const int* __restrict__ gfill,
                                                int* __restrict__ cursor,
                                                Edge* __restrict__ edges)
{
    int q   = blockIdx.x & (N_BUCKETS - 1);
    int idx = blockIdx.x >> 3;                 // 0..31 within bucket
    int d0 = q * BUCKET_NODES;
    #pragma unroll
    for (int g = 0; g < N_GROUPS; ++g) {
        int sub = q * N_GROUPS + g;
        int n = gfill[sub * GFILL_STRIDE];
        long long base = (long long)sub * SUBCAP;
        for (int i = idx * 256 + threadIdx.x; i < n; i += 32 * 256) {
            int2 st = staged[base + i];
            unsigned pack = (unsigned)st.y;
            int d = d0 + (int)(pack >> 16);
            int pos = atomicAdd(&cursor[d], 1);
            Edge ed; ed.s = st.x; ed.w = __uint_as_float((pack & 0xFFFFu) << 16);
            edges[pos] = ed;
        }
    }
}

// ---- gemm1_mfma: y = x @ W1 via v_mfma_f32_16x16x32_bf16 ------------------
__global__ __launch_bounds__(256) void gemm1_mfma(const float* __restrict__ x,
                                                  const float* __restrict__ W1,
                                                  __hip_bfloat16* __restrict__ y)
{
    __shared__ bf16x8 w1s[2048];                  // 32 KB
    int t = threadIdx.x;
    for (int f = t; f < 2048; f += 256) {         // 8 frags per thread
        int lane = f & 63;
        int nt = (f >> 6) & 7;
        int ks = f >> 9;
        int m = lane & 15, quad = lane >> 4;
        bf16x8 frag;
        #pragma unroll
        for (int j = 0; j < 8; ++j) {
            int k = ks * 32 + quad * 8 + j;
            frag[j] = (short)f32_to_bf16_bits(W1[k * HIDDEN + nt * 16 + m]);
        }
        w1s[f] = frag;
    }
    __syncthreads();

    int wv = t >> 6;
    int lane = t & 63;
    int m = lane & 15, quad = lane >> 4;
    int row0 = blockIdx.x * 64 + wv * 16;
    int arow = row0 + m;
    if (arow >= N_NODES) arow = N_NODES - 1;      // clamp loads; stores guarded

    bf16x8 afrag[4];
    #pragma unroll
    for (int ks = 0; ks < 4; ++ks) {
        const float4* xp = (const float4*)(x + (long long)arow * IN_DIM + ks * 32 + quad * 8);
        float4 a0 = xp[0], a1 = xp[1];
        afrag[ks][0] = (short)f32_to_bf16_bits(a0.x);
        afrag[ks][1] = (short)f32_to_bf16_bits(a0.y);
        afrag[ks][2] = (short)f32_to_bf16_bits(a0.z);
        afrag[ks][3] = (short)f32_to_bf16_bits(a0.w);
        afrag[ks][4] = (short)f32_to_bf16_bits(a1.x);
        afrag[ks][5] = (short)f32_to_bf16_bits(a1.y);
        afrag[ks][6] = (short)f32_to_bf16_bits(a1.z);
        afrag[ks][7] = (short)f32_to_bf16_bits(a1.w);
    }

    f32x4 acc[8];
    #pragma unroll
    for (int nt = 0; nt < 8; ++nt) acc[nt] = (f32x4){0.f, 0.f, 0.f, 0.f};

    #pragma unroll
    for (int ks = 0; ks < 4; ++ks) {
        #pragma unroll
        for (int nt = 0; nt < 8; ++nt) {
            bf16x8 bfrag = w1s[(ks * 8 + nt) * 64 + lane];
            acc[nt] = __builtin_amdgcn_mfma_f32_16x16x32_bf16(afrag[ks], bfrag, acc[nt], 0, 0, 0);
        }
    }

    #pragma unroll
    for (int nt = 0; nt < 8; ++nt) {
        #pragma unroll
        for (int r = 0; r < 4; ++r) {
            int rrow = row0 + quad * 4 + r;
            if (rrow < N_NODES)
                y[(long long)rrow * HIDDEN + nt * 16 + m] = __float2bfloat16(acc[nt][r]);
        }
    }
}

// ---- spmm1: h1 = relu(A @ y + b1); wave/node, bf16x2 per lane -------------
__global__ __launch_bounds__(256) void spmm1_kernel(const int* __restrict__ row_ptr,
                                                    const Edge* __restrict__ edges,
                                                    const __hip_bfloat16* __restrict__ y,
                                                    const float* __restrict__ b1,
                                                    __hip_bfloat16* __restrict__ h1)
{
    int node = blockIdx.x * 4 + (threadIdx.x >> 6);
    int lane = threadIdx.x & 63;
    if (node >= N_NODES) return;
    int beg = row_ptr[node];
    int end = row_ptr[node + 1];
    const __hip_bfloat162* yv = (const __hip_bfloat162*)y;
    float ax = 0.f, ay = 0.f;
    int j = beg;
    for (; j + 3 < end; j += 4) {
        Edge e0 = edges[j];
        Edge e1 = edges[j + 1];
        Edge e2 = edges[j + 2];
        Edge e3 = edges[j + 3];
        __hip_bfloat162 v0 = yv[(long long)e0.s * 64 + lane];
        __hip_bfloat162 v1 = yv[(long long)e1.s * 64 + lane];
        __hip_bfloat162 v2 = yv[(long long)e2.s * 64 + lane];
        __hip_bfloat162 v3 = yv[(long long)e3.s * 64 + lane];
        ax = fmaf(e0.w, __low2float(v0), ax);  ay = fmaf(e0.w, __high2float(v0), ay);
        ax = fmaf(e1.w, __low2float(v1), ax);  ay = fmaf(e1.w, __high2float(v1), ay);
        ax = fmaf(e2.w, __low2float(v2), ax);  ay = fmaf(e2.w, __high2float(v2), ay);
        ax = fmaf(e3.w, __low2float(v3), ax);  ay = fmaf(e3.w, __high2float(v3), ay);
    }
    for (; j < end; ++j) {
        Edge e0 = edges[j];
        __hip_bfloat162 v0 = yv[(long long)e0.s * 64 + lane];
        ax = fmaf(e0.w, __low2float(v0), ax);
        ay = fmaf(e0.w, __high2float(v0), ay);
    }
    float2 bv = ((const float2*)b1)[lane];
    __hip_bfloat162 hv;
    hv.x = __float2bfloat16(fmaxf(ax + bv.x, 0.f));
    hv.y = __float2bfloat16(fmaxf(ay + bv.y, 0.f));
    ((__hip_bfloat162*)h1)[(long long)node * 64 + lane] = hv;
}

// ---- gemm2: g = h1 @ W2 (bf16 in, bf16 out), 8 rows/block -----------------
#define G2_ROWS 8
__global__ __launch_bounds__(64) void gemm2_kernel(const __hip_bfloat16* __restrict__ h1,
                                                   const float* __restrict__ W2,
                                                   __hip_bfloat16* __restrict__ g)
{
    __shared__ float xs[G2_ROWS][HIDDEN];
    int row0 = blockIdx.x * G2_ROWS;
    int t = threadIdx.x;
    #pragma unroll
    for (int r = 0; r < G2_ROWS; ++r) {
        xs[r][t]      = __bfloat162float(h1[(long long)(row0 + r) * HIDDEN + t]);
        xs[r][t + 64] = __bfloat162float(h1[(long long)(row0 + r) * HIDDEN + t + 64]);
    }
    __syncthreads();
    if (t >= OUT_DIM) return;
    float acc[G2_ROWS];
    #pragma unroll
    for (int r = 0; r < G2_ROWS; ++r) acc[r] = 0.f;
    #pragma unroll 4
    for (int k = 0; k < HIDDEN; ++k) {
        float wv = W2[k * OUT_DIM + t];
        #pragma unroll
        for (int r = 0; r < G2_ROWS; ++r)
            acc[r] = fmaf(xs[r][k], wv, acc[r]);
    }
    #pragma unroll
    for (int r = 0; r < G2_ROWS; ++r)
        g[(long long)(row0 + r) * OUT_DIM + t] = __float2bfloat16(acc[r]);
}

// ---- spmm2: out = A @ g + b2; wave/node, 40 active lanes ------------------
__global__ __launch_bounds__(256) void spmm2_kernel(const int* __restrict__ row_ptr,
                                                    const Edge* __restrict__ edges,
                                                    const __hip_bfloat16* __restrict__ g,
                                                    const float* __restrict__ b2,
                                                    float* __restrict__ out)
{
    int node = blockIdx.x * 4 + (threadIdx.x >> 6);
    int lane = threadIdx.x & 63;
    if (node >= N_NODES) return;
    if (lane >= OUT_DIM) return;
    int beg = row_ptr[node];
    int end = row_ptr[node + 1];
    float acc = 0.f;
    int j = beg;
    for (; j + 3 < end; j += 4) {
        Edge e0 = edges[j];
        Edge e1 = edges[j + 1];
        Edge e2 = edges[j + 2];
        Edge e3 = edges[j + 3];
        float v0 = __bfloat162float(g[(long long)e0.s * OUT_DIM + lane]);
        float v1 = __bfloat162float(g[(long long)e1.s * OUT_DIM + lane]);
        float v2 = __bfloat162float(g[(long long)e2.s * OUT_DIM + lane]);
        float v3 = __bfloat162float(g[(long long)e3.s * OUT_DIM + lane]);
        acc = fmaf(e0.w, v0, acc);
        acc = fmaf(e1.w, v1, acc);
        acc = fmaf(e2.w, v2, acc);
        acc = fmaf(e3.w, v3, acc);
    }
    for (; j < end; ++j) {
        Edge e0 = edges[j];
        acc = fmaf(e0.w, __bfloat162float(g[(long long)e0.s * OUT_DIM + lane]), acc);
    }
    out[(long long)node * OUT_DIM + lane] = acc + b2[lane];
}

extern "C" void kernel_launch(void* const* d_in, const int* in_sizes, int n_in,
                              void* d_out, int out_size, void* d_ws, size_t ws_size,
                              hipStream_t stream)
{
    const float* x    = (const float*)d_in[0];
    const int*   esrc = (const int*)  d_in[1];
    const int*   edst = (const int*)  d_in[2];
    const float* ew   = (const float*)d_in[3];
    const float* W1   = (const float*)d_in[4];
    const float* b1   = (const float*)d_in[5];
    const float* W2   = (const float*)d_in[6];
    const float* b2   = (const float*)d_in[7];
    float* out = (float*)d_out;

    // workspace layout (~46 MB)
    __hip_bfloat16* y  = (__hip_bfloat16*)d_ws;                  // 12.8 MB
    __hip_bfloat16* h1 = y  + (size_t)N_NODES * HIDDEN;          // 12.8 MB
    __hip_bfloat16* g  = h1 + (size_t)N_NODES * HIDDEN;          // 4.0 MB
    int2* staged    = (int2*)(g + (size_t)N_NODES * OUT_DIM);    // 8.4 MB (64 sub-regions)
    Edge* edges     = (Edge*)(staged + (size_t)N_BUCKETS * N_GROUPS * SUBCAP); // 6.4 MB
    int* hist8      = (int*)(edges + N_EDGES);                   // 1.6 MB
    int* gfill      = hist8 + N_GROUPS * HIST_STRIDE;            // 64 line-padded counters
    int* cnt        = gfill + N_BUCKETS * N_GROUPS * GFILL_STRIDE; // 200 KB
    int* row_ptr    = cnt + 50176;                               // 50001 (pad 50176)
    int* cursor     = row_ptr + 50176;
    int* block_sums = cursor + 50176;                            // 64 ints

    // CSR build: single-pass hist+bin -> scan -> bucket-owned placement
    hipMemsetAsync(hist8, 0,
                   (N_GROUPS * HIST_STRIDE + N_BUCKETS * N_GROUPS * GFILL_STRIDE)
                   * sizeof(int), stream);
    buildA<<<BA_BLOCKS, 256, 0, stream>>>(esrc, edst, ew, hist8, gfill, staged);
    scan_partial<<<SCAN_BLOCKS, SCAN_BS, 0, stream>>>(hist8, cnt, block_sums);
    scan_final<<<SCAN_BLOCKS, SCAN_BS, 0, stream>>>(cnt, block_sums, row_ptr, cursor);
    scatterC<<<32 * N_BUCKETS, 256, 0, stream>>>(staged, gfill, cursor, edges);

    // y = x @ W1 (MFMA, W1 swizzled in-kernel via LDS)
    gemm1_mfma<<<(N_NODES + 63) / 64, 256, 0, stream>>>(x, W1, y);
    // h1 = relu(A @ y + b1)
    spmm1_kernel<<<(N_NODES + 3) / 4, 256, 0, stream>>>(row_ptr, edges, y, b1, h1);
    // g = h1 @ W2
    gemm2_kernel<<<N_NODES / G2_ROWS, 64, 0, stream>>>(h1, W2, g);
    // out = A @ g + b2
    spmm2_kernel<<<(N_NODES + 3) / 4, 256, 0, stream>>>(row_ptr, edges, g, b2, out);
}

// Round 15
// 267.029 us; speedup vs baseline: 1.1241x; 1.0070x over previous
//
#include <hip/hip_runtime.h>
#include <hip/hip_bf16.h>

#define N_NODES 50000
#define N_EDGES 800000
#define IN_DIM 128
#define HIDDEN 128
#define OUT_DIM 40

#define SCAN_BS 1024
#define SCAN_BLOCKS ((N_NODES + SCAN_BS - 1) / SCAN_BS)   // 49

#define N_BUCKETS 8
#define BUCKET_NODES (N_NODES / N_BUCKETS)                // 6250
#define HIST_STRIDE 50176                                 // line-aligned copy stride

#define SC_CHUNK 2048                                     // edges per scatter chunk
#define SC_CHUNKS ((N_EDGES + SC_CHUNK - 1) / SC_CHUNK)   // 391

struct __align__(8) Edge { int s; float w; };

typedef __attribute__((ext_vector_type(8))) short bf16x8;   // MFMA A/B frag (4 VGPR)
typedef __attribute__((ext_vector_type(4))) float f32x4;    // MFMA C/D frag

// fp32 -> bf16 bits with round-to-nearest-even
__device__ __forceinline__ unsigned f32_to_bf16_bits(float f) {
    unsigned u = __float_as_uint(f);
    return (u + 0x7FFFu + ((u >> 16) & 1u)) >> 16;
}

// ---- 1) hist: XCD-private per-node histogram (copy = blockIdx&7) ----------
__global__ __launch_bounds__(256) void hist_kernel(const int* __restrict__ dst,
                                                   int* __restrict__ hist8)
{
    int i = blockIdx.x * 256 + threadIdx.x;       // grid exact: 3125*256
    int copy = blockIdx.x & (N_BUCKETS - 1);
    atomicAdd(&hist8[copy * HIST_STRIDE + dst[i]], 1);
}

// ---- 2a) reduce 8 histogram copies -> cnt, plus per-block partial sums ----
__global__ __launch_bounds__(SCAN_BS) void scan_partial(const int* __restrict__ hist8,
                                                        int* __restrict__ cnt,
                                                        int* __restrict__ block_sums)
{
    __shared__ int red[SCAN_BS / 64];
    int i = blockIdx.x * SCAN_BS + threadIdx.x;
    int v = 0;
    if (i < N_NODES) {
        #pragma unroll
        for (int c = 0; c < N_BUCKETS; ++c) v += hist8[c * HIST_STRIDE + i];
        cnt[i] = v;
    }
    int s = v;
    for (int off = 32; off > 0; off >>= 1) s += __shfl_down(s, off, 64);
    int wave = threadIdx.x >> 6, lane = threadIdx.x & 63;
    if (lane == 0) red[wave] = s;
    __syncthreads();
    if (threadIdx.x == 0) {
        int tt = 0;
        #pragma unroll
        for (int wv = 0; wv < SCAN_BS / 64; ++wv) tt += red[wv];
        block_sums[blockIdx.x] = tt;
    }
}

// ---- 2b) block-local exclusive scan; inline prefix over raw block_sums ----
__global__ __launch_bounds__(SCAN_BS) void scan_final(const int* __restrict__ cnt,
                                                      const int* __restrict__ block_sums,
                                                      int* __restrict__ row_ptr,
                                                      int* __restrict__ cursor)
{
    __shared__ int tmp[SCAN_BS];
    __shared__ int blk_off;
    int t = threadIdx.x;
    int i = blockIdx.x * SCAN_BS + t;
    if (t == 0) {
        int s = 0;
        for (int j = 0; j < (int)blockIdx.x; ++j) s += block_sums[j];
        blk_off = s;
        if (blockIdx.x == 0) row_ptr[N_NODES] = N_EDGES;
    }
    int v = (i < N_NODES) ? cnt[i] : 0;
    tmp[t] = v;
    __syncthreads();
    for (int off = 1; off < SCAN_BS; off <<= 1) {
        int u = (t >= off) ? tmp[t - off] : 0;
        __syncthreads();
        tmp[t] += u;
        __syncthreads();
    }
    if (i < N_NODES) {
        int excl = tmp[t] - v + blk_off;
        row_ptr[i] = excl;
        cursor[i]  = excl;
    }
}

// ---- 3) scatter_direct: bucket-filtered direct placement ------------------
// block (chunk, q=blockIdx&7): stream 2048 edges, scatter only those with
// dst in bucket q -> cursor slice (25 KB) + edge slice (800 KB) are touched
// by one XCD only. 8x re-read of dst is sequential and cheap.
__global__ __launch_bounds__(256) void scatter_direct(const int* __restrict__ src,
                                                      const int* __restrict__ dst,
                                                      const float* __restrict__ w,
                                                      int* __restrict__ cursor,
                                                      Edge* __restrict__ edges)
{
    int q     = blockIdx.x & (N_BUCKETS - 1);
    int chunk = blockIdx.x >> 3;                  // 0..390
    int base  = chunk * SC_CHUNK;
    int lo = q * BUCKET_NODES;
    int hi = lo + BUCKET_NODES;
    #pragma unroll
    for (int r = 0; r < SC_CHUNK / 256; ++r) {
        int i = base + r * 256 + threadIdx.x;
        if (i < N_EDGES) {
            int d = dst[i];
            if (d >= lo && d < hi) {
                int pos = atomicAdd(&cursor[d], 1);
                Edge ed; ed.s = src[i]; ed.w = w[i];
                edges[pos] = ed;
            }
        }
    }
}

// ---- gemm1_mfma: y = x @ W1 via v_mfma_f32_16x16x32_bf16 ------------------
__global__ __launch_bounds__(256) void gemm1_mfma(const float* __restrict__ x,
                                                  const float* __restrict__ W1,
                                                  __hip_bfloat16* __restrict__ y)
{
    __shared__ bf16x8 w1s[2048];                  // 32 KB
    int t = threadIdx.x;
    for (int f = t; f < 2048; f += 256) {         // 8 frags per thread
        int lane = f & 63;
        int nt = (f >> 6) & 7;
        int ks = f >> 9;
        int m = lane & 15, quad = lane >> 4;
        bf16x8 frag;
        #pragma unroll
        for (int j = 0; j < 8; ++j) {
            int k = ks * 32 + quad * 8 + j;
            frag[j] = (short)f32_to_bf16_bits(W1[k * HIDDEN + nt * 16 + m]);
        }
        w1s[f] = frag;
    }
    __syncthreads();

    int wv = t >> 6;
    int lane = t & 63;
    int m = lane & 15, quad = lane >> 4;
    int row0 = blockIdx.x * 64 + wv * 16;
    int arow = row0 + m;
    if (arow >= N_NODES) arow = N_NODES - 1;      // clamp loads; stores guarded

    bf16x8 afrag[4];
    #pragma unroll
    for (int ks = 0; ks < 4; ++ks) {
        const float4* xp = (const float4*)(x + (long long)arow * IN_DIM + ks * 32 + quad * 8);
        float4 a0 = xp[0], a1 = xp[1];
        afrag[ks][0] = (short)f32_to_bf16_bits(a0.x);
        afrag[ks][1] = (short)f32_to_bf16_bits(a0.y);
        afrag[ks][2] = (short)f32_to_bf16_bits(a0.z);
        afrag[ks][3] = (short)f32_to_bf16_bits(a0.w);
        afrag[ks][4] = (short)f32_to_bf16_bits(a1.x);
        afrag[ks][5] = (short)f32_to_bf16_bits(a1.y);
        afrag[ks][6] = (short)f32_to_bf16_bits(a1.z);
        afrag[ks][7] = (short)f32_to_bf16_bits(a1.w);
    }

    f32x4 acc[8];
    #pragma unroll
    for (int nt = 0; nt < 8; ++nt) acc[nt] = (f32x4){0.f, 0.f, 0.f, 0.f};

    #pragma unroll
    for (int ks = 0; ks < 4; ++ks) {
        #pragma unroll
        for (int nt = 0; nt < 8; ++nt) {
            bf16x8 bfrag = w1s[(ks * 8 + nt) * 64 + lane];
            acc[nt] = __builtin_amdgcn_mfma_f32_16x16x32_bf16(afrag[ks], bfrag, acc[nt], 0, 0, 0);
        }
    }

    #pragma unroll
    for (int nt = 0; nt < 8; ++nt) {
        #pragma unroll
        for (int r = 0; r < 4; ++r) {
            int rrow = row0 + quad * 4 + r;
            if (rrow < N_NODES)
                y[(long long)rrow * HIDDEN + nt * 16 + m] = __float2bfloat16(acc[nt][r]);
        }
    }
}

// ---- spmm1: h1 = relu(A @ y + b1); wave/node, bf16x2 per lane -------------
__global__ __launch_bounds__(256) void spmm1_kernel(const int* __restrict__ row_ptr,
                                                    const Edge* __restrict__ edges,
                                                    const __hip_bfloat16* __restrict__ y,
                                                    const float* __restrict__ b1,
                                                    __hip_bfloat16* __restrict__ h1)
{
    int node = blockIdx.x * 4 + (threadIdx.x >> 6);
    int lane = threadIdx.x & 63;
    if (node >= N_NODES) return;
    int beg = row_ptr[node];
    int end = row_ptr[node + 1];
    const __hip_bfloat162* yv = (const __hip_bfloat162*)y;
    float ax = 0.f, ay = 0.f;
    int j = beg;
    for (; j + 3 < end; j += 4) {
        Edge e0 = edges[j];
        Edge e1 = edges[j + 1];
        Edge e2 = edges[j + 2];
        Edge e3 = edges[j + 3];
        __hip_bfloat162 v0 = yv[(long long)e0.s * 64 + lane];
        __hip_bfloat162 v1 = yv[(long long)e1.s * 64 + lane];
        __hip_bfloat162 v2 = yv[(long long)e2.s * 64 + lane];
        __hip_bfloat162 v3 = yv[(long long)e3.s * 64 + lane];
        ax = fmaf(e0.w, __low2float(v0), ax);  ay = fmaf(e0.w, __high2float(v0), ay);
        ax = fmaf(e1.w, __low2float(v1), ax);  ay = fmaf(e1.w, __high2float(v1), ay);
        ax = fmaf(e2.w, __low2float(v2), ax);  ay = fmaf(e2.w, __high2float(v2), ay);
        ax = fmaf(e3.w, __low2float(v3), ax);  ay = fmaf(e3.w, __high2float(v3), ay);
    }
    for (; j < end; ++j) {
        Edge e0 = edges[j];
        __hip_bfloat162 v0 = yv[(long long)e0.s * 64 + lane];
        ax = fmaf(e0.w, __low2float(v0), ax);
        ay = fmaf(e0.w, __high2float(v0), ay);
    }
    float2 bv = ((const float2*)b1)[lane];
    __hip_bfloat162 hv;
    hv.x = __float2bfloat16(fmaxf(ax + bv.x, 0.f));
    hv.y = __float2bfloat16(fmaxf(ay + bv.y, 0.f));
    ((__hip_bfloat162*)h1)[(long long)node * 64 + lane] = hv;
}

// ---- gemm2: g = h1 @ W2 (bf16 in, bf16 out), 8 rows/block -----------------
#define G2_ROWS 8
__global__ __launch_bounds__(64) void gemm2_kernel(const __hip_bfloat16* __restrict__ h1,
                                                   const float* __restrict__ W2,
                                                   __hip_bfloat16* __restrict__ g)
{
    __shared__ float xs[G2_ROWS][HIDDEN];
    int row0 = blockIdx.x * G2_ROWS;
    int t = threadIdx.x;
    #pragma unroll
    for (int r = 0; r < G2_ROWS; ++r) {
        xs[r][t]      = __bfloat162float(h1[(long long)(row0 + r) * HIDDEN + t]);
        xs[r][t + 64] = __bfloat162float(h1[(long long)(row0 + r) * HIDDEN + t + 64]);
    }
    __syncthreads();
    if (t >= OUT_DIM) return;
    float acc[G2_ROWS];
    #pragma unroll
    for (int r = 0; r < G2_ROWS; ++r) acc[r] = 0.f;
    #pragma unroll 4
    for (int k = 0; k < HIDDEN; ++k) {
        float wv = W2[k * OUT_DIM + t];
        #pragma unroll
        for (int r = 0; r < G2_ROWS; ++r)
            acc[r] = fmaf(xs[r][k], wv, acc[r]);
    }
    #pragma unroll
    for (int r = 0; r < G2_ROWS; ++r)
        g[(long long)(row0 + r) * OUT_DIM + t] = __float2bfloat16(acc[r]);
}

// ---- spmm2: out = A @ g + b2; wave/node, 40 active lanes ------------------
__global__ __launch_bounds__(256) void spmm2_kernel(const int* __restrict__ row_ptr,
                                                    const Edge* __restrict__ edges,
                                                    const __hip_bfloat16* __restrict__ g,
                                                    const float* __restrict__ b2,
                                                    float* __restrict__ out)
{
    int node = blockIdx.x * 4 + (threadIdx.x >> 6);
    int lane = threadIdx.x & 63;
    if (node >= N_NODES) return;
    if (lane >= OUT_DIM) return;
    int beg = row_ptr[node];
    int end = row_ptr[node + 1];
    float acc = 0.f;
    int j = beg;
    for (; j + 3 < end; j += 4) {
        Edge e0 = edges[j];
        Edge e1 = edges[j + 1];
        Edge e2 = edges[j + 2];
        Edge e3 = edges[j + 3];
        float v0 = __bfloat162float(g[(long long)e0.s * OUT_DIM + lane]);
        float v1 = __bfloat162float(g[(long long)e1.s * OUT_DIM + lane]);
        float v2 = __bfloat162float(g[(long long)e2.s * OUT_DIM + lane]);
        float v3 = __bfloat162float(g[(long long)e3.s * OUT_DIM + lane]);
        acc = fmaf(e0.w, v0, acc);
        acc = fmaf(e1.w, v1, acc);
        acc = fmaf(e2.w, v2, acc);
        acc = fmaf(e3.w, v3, acc);
    }
    for (; j < end; ++j) {
        Edge e0 = edges[j];
        acc = fmaf(e0.w, __bfloat162float(g[(long long)e0.s * OUT_DIM + lane]), acc);
    }
    out[(long long)node * OUT_DIM + lane] = acc + b2[lane];
}

extern "C" void kernel_launch(void* const* d_in, const int* in_sizes, int n_in,
                              void* d_out, int out_size, void* d_ws, size_t ws_size,
                              hipStream_t stream)
{
    const float* x    = (const float*)d_in[0];
    const int*   esrc = (const int*)  d_in[1];
    const int*   edst = (const int*)  d_in[2];
    const float* ew   = (const float*)d_in[3];
    const float* W1   = (const float*)d_in[4];
    const float* b1   = (const float*)d_in[5];
    const float* W2   = (const float*)d_in[6];
    const float* b2   = (const float*)d_in[7];
    float* out = (float*)d_out;

    // workspace layout (~38 MB)
    __hip_bfloat16* y  = (__hip_bfloat16*)d_ws;                  // 12.8 MB
    __hip_bfloat16* h1 = y  + (size_t)N_NODES * HIDDEN;          // 12.8 MB
    __hip_bfloat16* g  = h1 + (size_t)N_NODES * HIDDEN;          // 4.0 MB
    Edge* edges     = (Edge*)(g + (size_t)N_NODES * OUT_DIM);    // 6.4 MB
    int* hist8      = (int*)(edges + N_EDGES);                   // 1.6 MB
    int* cnt        = hist8 + N_BUCKETS * HIST_STRIDE;           // 200 KB
    int* row_ptr    = cnt + 50176;                               // 50001 (pad 50176)
    int* cursor     = row_ptr + 50176;
    int* block_sums = cursor + 50176;                            // 64 ints

    // CSR build: XCD-private hist -> scan -> bucket-filtered direct scatter
    hipMemsetAsync(hist8, 0, N_BUCKETS * HIST_STRIDE * sizeof(int), stream);
    hist_kernel<<<N_EDGES / 256, 256, 0, stream>>>(edst, hist8);
    scan_partial<<<SCAN_BLOCKS, SCAN_BS, 0, stream>>>(hist8, cnt, block_sums);
    scan_final<<<SCAN_BLOCKS, SCAN_BS, 0, stream>>>(cnt, block_sums, row_ptr, cursor);
    scatter_direct<<<SC_CHUNKS * N_BUCKETS, 256, 0, stream>>>(esrc, edst, ew,
                                                              cursor, edges);

    // y = x @ W1 (MFMA, W1 swizzled in-kernel via LDS)
    gemm1_mfma<<<(N_NODES + 63) / 64, 256, 0, stream>>>(x, W1, y);
    // h1 = relu(A @ y + b1)
    spmm1_kernel<<<(N_NODES + 3) / 4, 256, 0, stream>>>(row_ptr, edges, y, b1, h1);
    // g = h1 @ W2
    gemm2_kernel<<<N_NODES / G2_ROWS, 64, 0, stream>>>(h1, W2, g);
    // out = A @ g + b2
    spmm2_kernel<<<(N_NODES + 3) / 4, 256, 0, stream>>>(row_ptr, edges, g, b2, out);
}

// Round 16
// 254.096 us; speedup vs baseline: 1.1813x; 1.0509x over previous
//
#include <hip/hip_runtime.h>
#include <hip/hip_bf16.h>

#define N_NODES 50000
#define N_EDGES 800000
#define IN_DIM 128
#define HIDDEN 128
#define OUT_DIM 40

#define SCAN_BS 1024
#define SCAN_BLOCKS ((N_NODES + SCAN_BS - 1) / SCAN_BS)   // 49

#define N_BUCKETS 8
#define BUCKET_NODES (N_NODES / N_BUCKETS)                // 6250
#define HIST_STRIDE 50176                                 // line-aligned copy stride

#define SC_CHUNK 2048                                     // edges per scatter chunk
#define SC_CHUNKS ((N_EDGES + SC_CHUNK - 1) / SC_CHUNK)   // 391

struct __align__(8) Edge { int s; float w; };

typedef __attribute__((ext_vector_type(8))) short bf16x8;   // MFMA A/B frag (4 VGPR)
typedef __attribute__((ext_vector_type(4))) float f32x4;    // MFMA C/D frag

// fp32 -> bf16 bits with round-to-nearest-even
__device__ __forceinline__ unsigned f32_to_bf16_bits(float f) {
    unsigned u = __float_as_uint(f);
    return (u + 0x7FFFu + ((u >> 16) & 1u)) >> 16;
}

// ---- 1) hist: XCD-private histogram; RETURNING atomic gives each edge its
// rank within (copy, dst). rank saved to erank (coalesced 4B/edge).
__global__ __launch_bounds__(256) void hist_kernel(const int* __restrict__ dst,
                                                   int* __restrict__ hist8,
                                                   int* __restrict__ erank)
{
    int i = blockIdx.x * 256 + threadIdx.x;       // grid exact: 3125*256
    int copy = blockIdx.x & (N_BUCKETS - 1);
    erank[i] = atomicAdd(&hist8[copy * HIST_STRIDE + dst[i]], 1);
}

// ---- 2a) convert 8 copies -> per-copy exclusive offsets (in place),
// total into cnt, plus per-block partial sums for the scan ----------------
__global__ __launch_bounds__(SCAN_BS) void scan_partial(int* __restrict__ hist8,
                                                        int* __restrict__ cnt,
                                                        int* __restrict__ block_sums)
{
    __shared__ int red[SCAN_BS / 64];
    int i = blockIdx.x * SCAN_BS + threadIdx.x;
    int total = 0;
    if (i < N_NODES) {
        int off = 0;
        #pragma unroll
        for (int c = 0; c < N_BUCKETS; ++c) {
            int h = hist8[c * HIST_STRIDE + i];
            hist8[c * HIST_STRIDE + i] = off;     // exclusive prefix over copies
            off += h;
        }
        total = off;
        cnt[i] = total;
    }
    int s = total;
    for (int off = 32; off > 0; off >>= 1) s += __shfl_down(s, off, 64);
    int wave = threadIdx.x >> 6, lane = threadIdx.x & 63;
    if (lane == 0) red[wave] = s;
    __syncthreads();
    if (threadIdx.x == 0) {
        int tt = 0;
        #pragma unroll
        for (int wv = 0; wv < SCAN_BS / 64; ++wv) tt += red[wv];
        block_sums[blockIdx.x] = tt;
    }
}

// ---- 2b) block-local exclusive scan; inline prefix over raw block_sums ----
__global__ __launch_bounds__(SCAN_BS) void scan_final(const int* __restrict__ cnt,
                                                      const int* __restrict__ block_sums,
                                                      int* __restrict__ row_ptr)
{
    __shared__ int tmp[SCAN_BS];
    __shared__ int blk_off;
    int t = threadIdx.x;
    int i = blockIdx.x * SCAN_BS + t;
    if (t == 0) {
        int s = 0;
        for (int j = 0; j < (int)blockIdx.x; ++j) s += block_sums[j];
        blk_off = s;
        if (blockIdx.x == 0) row_ptr[N_NODES] = N_EDGES;
    }
    int v = (i < N_NODES) ? cnt[i] : 0;
    tmp[t] = v;
    __syncthreads();
    for (int off = 1; off < SCAN_BS; off <<= 1) {
        int u = (t >= off) ? tmp[t - off] : 0;
        __syncthreads();
        tmp[t] += u;
        __syncthreads();
    }
    if (i < N_NODES) row_ptr[i] = tmp[t] - v + blk_off;
}

// ---- 3) scatter_det: deterministic bucket-filtered placement, NO atomics.
// pos = row_ptr[d] + off8[copy(i)][d] + erank[i]; bucket q = blockIdx&7 owns
// the destination slice (one XCD) so the 8B writes merge in its L2.
__global__ __launch_bounds__(256) void scatter_det(const int* __restrict__ src,
                                                   const int* __restrict__ dst,
                                                   const float* __restrict__ w,
                                                   const int* __restrict__ hist8,
                                                   const int* __restrict__ erank,
                                                   const int* __restrict__ row_ptr,
                                                   Edge* __restrict__ edges)
{
    int q     = blockIdx.x & (N_BUCKETS - 1);
    int chunk = blockIdx.x >> 3;                  // 0..390
    int base  = chunk * SC_CHUNK;
    int lo = q * BUCKET_NODES;
    int hi = lo + BUCKET_NODES;
    #pragma unroll
    for (int r = 0; r < SC_CHUNK / 256; ++r) {
        int i = base + r * 256 + threadIdx.x;
        if (i < N_EDGES) {
            int d = dst[i];
            if (d >= lo && d < hi) {
                int copy = (i >> 8) & (N_BUCKETS - 1);   // == hist's blockIdx&7
                int pos = row_ptr[d] + hist8[copy * HIST_STRIDE + d] + erank[i];
                Edge ed; ed.s = src[i]; ed.w = w[i];
                edges[pos] = ed;
            }
        }
    }
}

// ---- gemm1_mfma: y = x @ W1 via v_mfma_f32_16x16x32_bf16 ------------------
__global__ __launch_bounds__(256) void gemm1_mfma(const float* __restrict__ x,
                                                  const float* __restrict__ W1,
                                                  __hip_bfloat16* __restrict__ y)
{
    __shared__ bf16x8 w1s[2048];                  // 32 KB
    int t = threadIdx.x;
    for (int f = t; f < 2048; f += 256) {         // 8 frags per thread
        int lane = f & 63;
        int nt = (f >> 6) & 7;
        int ks = f >> 9;
        int m = lane & 15, quad = lane >> 4;
        bf16x8 frag;
        #pragma unroll
        for (int j = 0; j < 8; ++j) {
            int k = ks * 32 + quad * 8 + j;
            frag[j] = (short)f32_to_bf16_bits(W1[k * HIDDEN + nt * 16 + m]);
        }
        w1s[f] = frag;
    }
    __syncthreads();

    int wv = t >> 6;
    int lane = t & 63;
    int m = lane & 15, quad = lane >> 4;
    int row0 = blockIdx.x * 64 + wv * 16;
    int arow = row0 + m;
    if (arow >= N_NODES) arow = N_NODES - 1;      // clamp loads; stores guarded

    bf16x8 afrag[4];
    #pragma unroll
    for (int ks = 0; ks < 4; ++ks) {
        const float4* xp = (const float4*)(x + (long long)arow * IN_DIM + ks * 32 + quad * 8);
        float4 a0 = xp[0], a1 = xp[1];
        afrag[ks][0] = (short)f32_to_bf16_bits(a0.x);
        afrag[ks][1] = (short)f32_to_bf16_bits(a0.y);
        afrag[ks][2] = (short)f32_to_bf16_bits(a0.z);
        afrag[ks][3] = (short)f32_to_bf16_bits(a0.w);
        afrag[ks][4] = (short)f32_to_bf16_bits(a1.x);
        afrag[ks][5] = (short)f32_to_bf16_bits(a1.y);
        afrag[ks][6] = (short)f32_to_bf16_bits(a1.z);
        afrag[ks][7] = (short)f32_to_bf16_bits(a1.w);
    }

    f32x4 acc[8];
    #pragma unroll
    for (int nt = 0; nt < 8; ++nt) acc[nt] = (f32x4){0.f, 0.f, 0.f, 0.f};

    #pragma unroll
    for (int ks = 0; ks < 4; ++ks) {
        #pragma unroll
        for (int nt = 0; nt < 8; ++nt) {
            bf16x8 bfrag = w1s[(ks * 8 + nt) * 64 + lane];
            acc[nt] = __builtin_amdgcn_mfma_f32_16x16x32_bf16(afrag[ks], bfrag, acc[nt], 0, 0, 0);
        }
    }

    #pragma unroll
    for (int nt = 0; nt < 8; ++nt) {
        #pragma unroll
        for (int r = 0; r < 4; ++r) {
            int rrow = row0 + quad * 4 + r;
            if (rrow < N_NODES)
                y[(long long)rrow * HIDDEN + nt * 16 + m] = __float2bfloat16(acc[nt][r]);
        }
    }
}

// ---- spmm1: h1 = relu(A @ y + b1); wave/node, bf16x2 per lane -------------
__global__ __launch_bounds__(256) void spmm1_kernel(const int* __restrict__ row_ptr,
                                                    const Edge* __restrict__ edges,
                                                    const __hip_bfloat16* __restrict__ y,
                                                    const float* __restrict__ b1,
                                                    __hip_bfloat16* __restrict__ h1)
{
    int node = blockIdx.x * 4 + (threadIdx.x >> 6);
    int lane = threadIdx.x & 63;
    if (node >= N_NODES) return;
    int beg = row_ptr[node];
    int end = row_ptr[node + 1];
    const __hip_bfloat162* yv = (const __hip_bfloat162*)y;
    float ax = 0.f, ay = 0.f;
    int j = beg;
    for (; j + 3 < end; j += 4) {
        Edge e0 = edges[j];
        Edge e1 = edges[j + 1];
        Edge e2 = edges[j + 2];
        Edge e3 = edges[j + 3];
        __hip_bfloat162 v0 = yv[(long long)e0.s * 64 + lane];
        __hip_bfloat162 v1 = yv[(long long)e1.s * 64 + lane];
        __hip_bfloat162 v2 = yv[(long long)e2.s * 64 + lane];
        __hip_bfloat162 v3 = yv[(long long)e3.s * 64 + lane];
        ax = fmaf(e0.w, __low2float(v0), ax);  ay = fmaf(e0.w, __high2float(v0), ay);
        ax = fmaf(e1.w, __low2float(v1), ax);  ay = fmaf(e1.w, __high2float(v1), ay);
        ax = fmaf(e2.w, __low2float(v2), ax);  ay = fmaf(e2.w, __high2float(v2), ay);
        ax = fmaf(e3.w, __low2float(v3), ax);  ay = fmaf(e3.w, __high2float(v3), ay);
    }
    for (; j < end; ++j) {
        Edge e0 = edges[j];
        __hip_bfloat162 v0 = yv[(long long)e0.s * 64 + lane];
        ax = fmaf(e0.w, __low2float(v0), ax);
        ay = fmaf(e0.w, __high2float(v0), ay);
    }
    float2 bv = ((const float2*)b1)[lane];
    __hip_bfloat162 hv;
    hv.x = __float2bfloat16(fmaxf(ax + bv.x, 0.f));
    hv.y = __float2bfloat16(fmaxf(ay + bv.y, 0.f));
    ((__hip_bfloat162*)h1)[(long long)node * 64 + lane] = hv;
}

// ---- gemm2: g = h1 @ W2 (bf16 in, bf16 out), 8 rows/block -----------------
#define G2_ROWS 8
__global__ __launch_bounds__(64) void gemm2_kernel(const __hip_bfloat16* __restrict__ h1,
                                                   const float* __restrict__ W2,
                                                   __hip_bfloat16* __restrict__ g)
{
    __shared__ float xs[G2_ROWS][HIDDEN];
    int row0 = blockIdx.x * G2_ROWS;
    int t = threadIdx.x;
    #pragma unroll
    for (int r = 0; r < G2_ROWS; ++r) {
        xs[r][t]      = __bfloat162float(h1[(long long)(row0 + r) * HIDDEN + t]);
        xs[r][t + 64] = __bfloat162float(h1[(long long)(row0 + r) * HIDDEN + t + 64]);
    }
    __syncthreads();
    if (t >= OUT_DIM) return;
    float acc[G2_ROWS];
    #pragma unroll
    for (int r = 0; r < G2_ROWS; ++r) acc[r] = 0.f;
    #pragma unroll 4
    for (int k = 0; k < HIDDEN; ++k) {
        float wv = W2[k * OUT_DIM + t];
        #pragma unroll
        for (int r = 0; r < G2_ROWS; ++r)
            acc[r] = fmaf(xs[r][k], wv, acc[r]);
    }
    #pragma unroll
    for (int r = 0; r < G2_ROWS; ++r)
        g[(long long)(row0 + r) * OUT_DIM + t] = __float2bfloat16(acc[r]);
}

// ---- spmm2: out = A @ g + b2; wave/node, 40 active lanes ------------------
__global__ __launch_bounds__(256) void spmm2_kernel(const int* __restrict__ row_ptr,
                                                    const Edge* __restrict__ edges,
                                                    const __hip_bfloat16* __restrict__ g,
                                                    const float* __restrict__ b2,
                                                    float* __restrict__ out)
{
    int node = blockIdx.x * 4 + (threadIdx.x >> 6);
    int lane = threadIdx.x & 63;
    if (node >= N_NODES) return;
    if (lane >= OUT_DIM) return;
    int beg = row_ptr[node];
    int end = row_ptr[node + 1];
    float acc = 0.f;
    int j = beg;
    for (; j + 3 < end; j += 4) {
        Edge e0 = edges[j];
        Edge e1 = edges[j + 1];
        Edge e2 = edges[j + 2];
        Edge e3 = edges[j + 3];
        float v0 = __bfloat162float(g[(long long)e0.s * OUT_DIM + lane]);
        float v1 = __bfloat162float(g[(long long)e1.s * OUT_DIM + lane]);
        float v2 = __bfloat162float(g[(long long)e2.s * OUT_DIM + lane]);
        float v3 = __bfloat162float(g[(long long)e3.s * OUT_DIM + lane]);
        acc = fmaf(e0.w, v0, acc);
        acc = fmaf(e1.w, v1, acc);
        acc = fmaf(e2.w, v2, acc);
        acc = fmaf(e3.w, v3, acc);
    }
    for (; j < end; ++j) {
        Edge e0 = edges[j];
        acc = fmaf(e0.w, __bfloat162float(g[(long long)e0.s * OUT_DIM + lane]), acc);
    }
    out[(long long)node * OUT_DIM + lane] = acc + b2[lane];
}

extern "C" void kernel_launch(void* const* d_in, const int* in_sizes, int n_in,
                              void* d_out, int out_size, void* d_ws, size_t ws_size,
                              hipStream_t stream)
{
    const float* x    = (const float*)d_in[0];
    const int*   esrc = (const int*)  d_in[1];
    const int*   edst = (const int*)  d_in[2];
    const float* ew   = (const float*)d_in[3];
    const float* W1   = (const float*)d_in[4];
    const float* b1   = (const float*)d_in[5];
    const float* W2   = (const float*)d_in[6];
    const float* b2   = (const float*)d_in[7];
    float* out = (float*)d_out;

    // workspace layout (~41 MB)
    __hip_bfloat16* y  = (__hip_bfloat16*)d_ws;                  // 12.8 MB
    __hip_bfloat16* h1 = y  + (size_t)N_NODES * HIDDEN;          // 12.8 MB
    __hip_bfloat16* g  = h1 + (size_t)N_NODES * HIDDEN;          // 4.0 MB
    Edge* edges     = (Edge*)(g + (size_t)N_NODES * OUT_DIM);    // 6.4 MB
    int* hist8      = (int*)(edges + N_EDGES);                   // 1.6 MB
    int* erank      = hist8 + N_BUCKETS * HIST_STRIDE;           // 3.2 MB
    int* cnt        = erank + N_EDGES;                           // 200 KB
    int* row_ptr    = cnt + 50176;                               // 50001 (pad 50176)
    int* block_sums = row_ptr + 50176;                           // 64 ints

    // CSR build: ranked hist -> offset conversion + scan -> atomic-free scatter
    hipMemsetAsync(hist8, 0, N_BUCKETS * HIST_STRIDE * sizeof(int), stream);
    hist_kernel<<<N_EDGES / 256, 256, 0, stream>>>(edst, hist8, erank);
    scan_partial<<<SCAN_BLOCKS, SCAN_BS, 0, stream>>>(hist8, cnt, block_sums);
    scan_final<<<SCAN_BLOCKS, SCAN_BS, 0, stream>>>(cnt, block_sums, row_ptr);
    scatter_det<<<SC_CHUNKS * N_BUCKETS, 256, 0, stream>>>(esrc, edst, ew, hist8,
                                                           erank, row_ptr, edges);

    // y = x @ W1 (MFMA, W1 swizzled in-kernel via LDS)
    gemm1_mfma<<<(N_NODES + 63) / 64, 256, 0, stream>>>(x, W1, y);
    // h1 = relu(A @ y + b1)
    spmm1_kernel<<<(N_NODES + 3) / 4, 256, 0, stream>>>(row_ptr, edges, y, b1, h1);
    // g = h1 @ W2
    gemm2_kernel<<<N_NODES / G2_ROWS, 64, 0, stream>>>(h1, W2, g);
    // out = A @ g + b2
    spmm2_kernel<<<(N_NODES + 3) / 4, 256, 0, stream>>>(row_ptr, edges, g, b2, out);
}